// Round 1
// baseline (1234.408 us; speedup 1.0000x reference)
//
#include <hip/hip_runtime.h>
#include <hip/hip_bf16.h>

#define B_TOK 65536
#define HDIM  1024
#define EXP   16
#define IDIM  1024

typedef __attribute__((ext_vector_type(8))) short bf16x8_t;   // 8 bf16 (4 VGPRs)
typedef __attribute__((ext_vector_type(4))) float f32x4_t;    // 4 fp32 acc

// ---- helpers ---------------------------------------------------------------

__device__ __forceinline__ unsigned short f2bf(float f) {
    unsigned int u = __float_as_uint(f);
    unsigned int r = (u + 0x7FFFu + ((u >> 16) & 1u)) >> 16;   // RNE
    return (unsigned short)r;
}

__device__ __forceinline__ void async_load16(const void* g, void* l) {
    __builtin_amdgcn_global_load_lds(
        (const __attribute__((address_space(1))) unsigned int*)g,
        (__attribute__((address_space(3))) unsigned int*)l,
        16, 0, 0);
}

// ---- kernel 1: gate (scores + argmax) fused with x f32->bf16 ---------------
// grid 1024 x 256. Each wave handles 16 tokens (4 iters of 4, register-blocked
// so each LDS Wg read is reused by 4 tokens).
__global__ __launch_bounds__(256) void gate_kernel(
    const float* __restrict__ x, const float* __restrict__ Wg,
    unsigned short* __restrict__ xbf, int* __restrict__ eidx)
{
    __shared__ float wg[EXP * HDIM];          // 64 KB
    const int tid = threadIdx.x;
    { // cooperative Wg load, coalesced float4
        const float4* s = (const float4*)Wg;
        float4* d = (float4*)wg;
        for (int i = tid; i < EXP * HDIM / 4; i += 256) d[i] = s[i];
    }
    __syncthreads();

    const int wid = tid >> 6, lane = tid & 63;
    const int gw = blockIdx.x * 4 + wid;      // 4096 waves

    for (int it = 0; it < 4; ++it) {
        const int t0 = gw * 16 + it * 4;
        float4 xv[4][4];
        float acc[4][EXP];
        for (int t = 0; t < 4; ++t) {
            const float* row = x + (size_t)(t0 + t) * HDIM;
            for (int j = 0; j < 4; ++j)
                xv[t][j] = *(const float4*)(row + j * 256 + lane * 4);
        }
        for (int t = 0; t < 4; ++t)
            for (int e = 0; e < EXP; ++e) acc[t][e] = 0.f;

        for (int j = 0; j < 4; ++j) {
            for (int e = 0; e < EXP; ++e) {
                float4 wv = *(const float4*)(wg + e * HDIM + j * 256 + lane * 4);
                for (int t = 0; t < 4; ++t) {
                    acc[t][e] += xv[t][j].x * wv.x + xv[t][j].y * wv.y
                               + xv[t][j].z * wv.z + xv[t][j].w * wv.w;
                }
            }
        }
        // bf16 store of x (coalesced: lanes write contiguous 8B)
        for (int t = 0; t < 4; ++t) {
            unsigned short* orow = xbf + (size_t)(t0 + t) * HDIM;
            for (int j = 0; j < 4; ++j) {
                ushort4 o;
                o.x = f2bf(xv[t][j].x); o.y = f2bf(xv[t][j].y);
                o.z = f2bf(xv[t][j].z); o.w = f2bf(xv[t][j].w);
                *(ushort4*)(orow + j * 256 + lane * 4) = o;
            }
        }
        // reduce + argmax (first-max-wins == np.argmax)
        for (int t = 0; t < 4; ++t) {
            float s[EXP];
            for (int e = 0; e < EXP; ++e) s[e] = acc[t][e];
            for (int d = 32; d >= 1; d >>= 1)
                for (int e = 0; e < EXP; ++e) s[e] += __shfl_xor(s[e], d, 64);
            int best = 0; float bv = s[0];
            for (int e = 1; e < EXP; ++e)
                if (s[e] > bv) { bv = s[e]; best = e; }
            if (lane == 0) eidx[t0 + t] = best;
        }
    }
}

// ---- kernel 2: We f32 -> bf16 ----------------------------------------------
__global__ __launch_bounds__(256) void convert_we(
    const float* __restrict__ we, unsigned short* __restrict__ webf)
{
    const size_t n4 = (size_t)EXP * IDIM * HDIM / 4;
    const size_t stride = (size_t)gridDim.x * 256;
    for (size_t i = (size_t)blockIdx.x * 256 + threadIdx.x; i < n4; i += stride) {
        float4 v = ((const float4*)we)[i];
        ushort4 o;
        o.x = f2bf(v.x); o.y = f2bf(v.y); o.z = f2bf(v.z); o.w = f2bf(v.w);
        ((ushort4*)webf)[i] = o;
    }
}

// ---- kernel 3: per-expert token-list build (ballot compaction) -------------
__global__ __launch_bounds__(64) void scatter_kernel(
    const int* __restrict__ eidx, int* __restrict__ token_list,
    int* __restrict__ counts)
{
    const int e = blockIdx.x, lane = threadIdx.x;
    int* tl = token_list + (size_t)e * B_TOK;
    int cnt = 0;
    for (int base = 0; base < B_TOK; base += 64) {
        const int b = base + lane;
        const bool m = (eidx[b] == e);
        unsigned long long mask = __ballot(m);
        if (m) {
            int pos = __popcll(mask & ((1ull << lane) - 1ull));
            tl[cnt + pos] = b;
        }
        cnt += __popcll(mask);
    }
    if (lane == 0) counts[e] = cnt;
}

// ---- kernel 4: grouped GEMM (m97 structure, gathered A rows) ---------------
// grid (8 n-tiles, 512 m-tiles, 16 experts), 256 threads = 4 waves (2x2).
// out[tok][n] = sum_k xbf[tok][k] * webf[e][n][k]   (both operands K-major)
__global__ __launch_bounds__(256) void moe_gemm(
    const unsigned short* __restrict__ xbf,
    const unsigned short* __restrict__ webf,
    const int* __restrict__ token_list,
    const int* __restrict__ counts,
    float* __restrict__ out)
{
    const int e = blockIdx.z;
    const int cnt = counts[e];
    const int m0 = blockIdx.y * 128;
    if (m0 >= cnt) return;
    const int row_count = min(128, cnt - m0);
    const int n0 = blockIdx.x * 128;

    __shared__ unsigned short As[128 * 64];   // 16 KB, [row][k] k-contig
    __shared__ unsigned short Bs[128 * 64];   // 16 KB

    const int tid = threadIdx.x;
    const int wid = tid >> 6, lane = tid & 63;
    const int rgrp = tid >> 3;                // 0..31: row within 32-row chunk
    const int kseg = tid & 7;                 // 16B segment within 128B row

    const int* tl = token_list + (size_t)e * B_TOK + m0;
    size_t abase[4], bbase[4];
    for (int i = 0; i < 4; ++i) {
        const int r = i * 32 + rgrp;
        const int tok = tl[min(r, row_count - 1)];
        abase[i] = ((size_t)tok * HDIM + kseg * 8) * 2;
        bbase[i] = (((size_t)e * IDIM + n0 + r) * HDIM + kseg * 8) * 2;
    }
    const char* xg = (const char*)xbf;
    const char* wp = (const char*)webf;

    f32x4_t acc[4][4];
    const f32x4_t z = {0.f, 0.f, 0.f, 0.f};
    for (int mi = 0; mi < 4; ++mi)
        for (int ni = 0; ni < 4; ++ni) acc[mi][ni] = z;

    const int wm = wid >> 1, wn = wid & 1;
    const int quad = lane >> 4, l16 = lane & 15;
    const int a_off = (wm * 64 + l16) * 64 + quad * 8;   // shorts
    const int b_off = (wn * 64 + l16) * 64 + quad * 8;

    for (int k0 = 0; k0 < HDIM; k0 += 64) {
        for (int i = 0; i < 4; ++i) {
            async_load16(xg + abase[i] + (size_t)k0 * 2, (char*)As + i * 4096 + tid * 16);
            async_load16(wp + bbase[i] + (size_t)k0 * 2, (char*)Bs + i * 4096 + tid * 16);
        }
        __builtin_amdgcn_s_waitcnt(0);
        __syncthreads();

        for (int kk = 0; kk < 64; kk += 32) {
            bf16x8_t av[4], bv[4];
            for (int mi = 0; mi < 4; ++mi)
                av[mi] = *(const bf16x8_t*)(As + a_off + mi * 16 * 64 + kk);
            for (int ni = 0; ni < 4; ++ni)
                bv[ni] = *(const bf16x8_t*)(Bs + b_off + ni * 16 * 64 + kk);
            for (int mi = 0; mi < 4; ++mi)
                for (int ni = 0; ni < 4; ++ni)
                    acc[mi][ni] = __builtin_amdgcn_mfma_f32_16x16x32_bf16(
                        av[mi], bv[ni], acc[mi][ni], 0, 0, 0);
        }
        __syncthreads();
    }

    // epilogue: C/D layout col = lane&15, row = (lane>>4)*4 + reg
    for (int mi = 0; mi < 4; ++mi) {
        const int rl0 = wm * 64 + mi * 16 + quad * 4;
        for (int r = 0; r < 4; ++r) {
            const int rl = rl0 + r;
            if (rl < row_count) {
                const int tok = tl[rl];
                float* orow = out + (size_t)tok * IDIM + n0 + wn * 64 + l16;
                for (int ni = 0; ni < 4; ++ni)
                    orow[ni * 16] = acc[mi][ni][r];
            }
        }
    }
}

// ---- launcher --------------------------------------------------------------
extern "C" void kernel_launch(void* const* d_in, const int* in_sizes, int n_in,
                              void* d_out, int out_size, void* d_ws, size_t ws_size,
                              hipStream_t stream) {
    const float* x  = (const float*)d_in[0];
    const float* Wg = (const float*)d_in[1];
    const float* We = (const float*)d_in[2];
    float* out = (float*)d_out;

    char* ws = (char*)d_ws;
    // ws layout (bytes):
    //   [0, 128 MiB)        x_bf16   [65536][1024]
    //   [+,  32 MiB)        we_bf16  [16][1024][1024]
    //   [+, 256 KiB)        eidx     [65536] int
    //   [+, 256 B  )        counts   [16] int
    //   [+,   4 MiB)        token_list [16][65536] int
    unsigned short* xbf   = (unsigned short*)(ws);
    unsigned short* webf  = (unsigned short*)(ws + 134217728);
    int*            eidx  = (int*)(ws + 167772160);
    int*            cnts  = (int*)(ws + 168034304);
    int*            tlist = (int*)(ws + 168034560);

    gate_kernel<<<1024, 256, 0, stream>>>(x, Wg, xbf, eidx);
    convert_we<<<4096, 256, 0, stream>>>(We, webf);
    scatter_kernel<<<16, 64, 0, stream>>>(eidx, tlist, cnts);
    moe_gemm<<<dim3(8, 512, 16), 256, 0, stream>>>(xbf, webf, tlist, cnts, out);
}